// Round 12
// baseline (1150.140 us; speedup 1.0000x reference)
//
#include <hip/hip_runtime.h>

#define NN 16000   // nodes
#define NE 64000   // edges
#define HD 90      // hidden
#define NG 512     // graphs

typedef float f32x4 __attribute__((ext_vector_type(4)));
typedef float f32x16 __attribute__((ext_vector_type(16)));
typedef short s16x8 __attribute__((ext_vector_type(8)));

// round-half-up f32 -> bf16
__device__ __forceinline__ unsigned short rhu1(float f) {
  return (unsigned short)((__builtin_bit_cast(unsigned int, f) + 0x8000u) >> 16);
}
// pack two f32 -> bf16x2 (lo in low half), RHU rounding
__device__ __forceinline__ unsigned int rhu_pack(float lo, float hi) {
  unsigned int ul = __builtin_bit_cast(unsigned int, lo) + 0x8000u;
  unsigned int uh = __builtin_bit_cast(unsigned int, hi) + 0x8000u;
  return __builtin_amdgcn_perm(uh, ul, 0x07060302u);
}
__device__ __forceinline__ float bfhi(unsigned int u) {
  return __builtin_bit_cast(float, u & 0xFFFF0000u);
}
__device__ __forceinline__ float bflo(unsigned int u) {
  return __builtin_bit_cast(float, u << 16);
}

// h0 = concat(x, pos) : [NN, 16]
__global__ void concat_kernel(const float* __restrict__ x, const float* __restrict__ pos,
                              float* __restrict__ h0) {
  int idx = blockIdx.x * 256 + threadIdx.x;
  if (idx >= NN * 16) return;
  int n = idx >> 4, c = idx & 15;
  h0[idx] = (c < 13) ? x[n * 13 + c] : pos[n * 3 + (c - 13)];
}

// he_bf[e][k] : [NE, 96] bf16. k<90: relu(edge MLP); k==90: 1.0 (bias row); k>90: 0
__global__ void edge_mlp_bf(const float* __restrict__ ea, const float* __restrict__ w1,
                            const float* __restrict__ b1, unsigned short* __restrict__ he) {
  int idx = blockIdx.x * 256 + threadIdx.x;
  if (idx >= NE * 96) return;
  int e = idx / 96, k = idx - e * 96;
  unsigned short v;
  if (k < 90) {
    const float* a = ea + e * 8;
    float acc = b1[k];
#pragma unroll
    for (int j = 0; j < 8; j++) acc = fmaf(a[j], w1[j * HD + k], acc);
    v = rhu1(fmaxf(acc, 0.f));
  } else {
    v = (k == 90) ? (unsigned short)0x3F80 : (unsigned short)0;  // bf16(1.0) / 0
  }
  he[idx] = v;
}

// W' prep, 32x32x16 B-fragment order: shorts as [i][ot(NOT)][c(6)][lane(64)][j(8)]
//   o = ot*32 + (lane&31), hk = c*16 + (lane>>5)*8 + j
//   hk<90 -> w2[hk][i*OC+o]; hk==90 -> b2[i*OC+o]; else 0.  One block per i.
template <int OC, int NOT>
__global__ void wprep_frag32(const float* __restrict__ w2, const float* __restrict__ b2,
                             unsigned short* __restrict__ wout, int inc_oc) {
  const int i = blockIdx.x;
  unsigned int* wo = (unsigned int*)(wout + (size_t)i * NOT * 6 * 512);
  for (int u = threadIdx.x; u < NOT * 6 * 256; u += 256) {
    int f = u >> 8, r = u & 255;
    int ot = f / 6;
    int c = f - 6 * ot;
    int lane = r >> 2, uu = r & 3;
    int o = ot * 32 + (lane & 31);
    int hk = c * 16 + ((lane >> 5) << 3) + 2 * uu;
    float v0 = 0.f, v1 = 0.f;
    if (o < OC) {
      if (hk < 90) v0 = w2[hk * inc_oc + i * OC + o];
      else if (hk == 90) v0 = b2[i * OC + o];
      int hk1 = hk + 1;
      if (hk1 < 90) v1 = w2[hk1 * inc_oc + i * OC + o];
      else if (hk1 == 90) v1 = b2[i * OC + o];
    }
    wo[u] = rhu_pack(v0, v1);
  }
}

// ---- msg kernel pipeline macros (plain arrays, constant post-unroll indices) ----
#define LOADB(II, B)                                                           \
  do {                                                                         \
    const unsigned short* wg_ = wl + ((size_t)((II) * NOT + wn) * 6 + kh3) * 512; \
    B[0] = *(const s16x8*)(wg_);                                               \
    B[1] = *(const s16x8*)(wg_ + 512);                                         \
    B[2] = *(const s16x8*)(wg_ + 1024);                                        \
  } while (0)

#define BODY(II, B)                                                            \
  do {                                                                         \
    _Pragma("unroll")                                                          \
    for (int mt = 0; mt < 2; mt++) {                                           \
      const int zbase = (II) * 64 + mt * 32 + h * 16;                          \
      const uint4 za = *(const uint4*)&zb[zbase];                              \
      const uint4 zc = *(const uint4*)&zb[zbase + 8];                          \
      f32x16 t = __builtin_amdgcn_mfma_f32_32x32x16_bf16(af[mt][0], B[0], (f32x16)0.f, 0, 0, 0); \
      t = __builtin_amdgcn_mfma_f32_32x32x16_bf16(af[mt][1], B[1], t, 0, 0, 0);\
      t = __builtin_amdgcn_mfma_f32_32x32x16_bf16(af[mt][2], B[2], t, 0, 0, 0);\
      f32x16 zv;                                                               \
      zv[0] = bflo(za.x);  zv[1] = bfhi(za.x);  zv[2] = bflo(za.y);  zv[3] = bfhi(za.y); \
      zv[4] = bflo(za.z);  zv[5] = bfhi(za.z);  zv[6] = bflo(za.w);  zv[7] = bfhi(za.w); \
      zv[8] = bflo(zc.x);  zv[9] = bfhi(zc.x);  zv[10] = bflo(zc.y); zv[11] = bfhi(zc.y); \
      zv[12] = bflo(zc.z); zv[13] = bfhi(zc.z); zv[14] = bflo(zc.w); zv[15] = bfhi(zc.w); \
      acc[mt] += zv * t;                                                       \
    }                                                                          \
  } while (0)

// Fused message GEMM + scatter, i-outer, barrier-free K-loop, 32x32x16 core,
// K-split wave specialization (R11), now with:
//  - LDS shrunk to ~12.5 KB: merge buffer ALIASES zb (dead after K-loop) and
//    the K-half merge runs one m-tile at a time (the 36 KB LDS of R10/R11
//    capped residency at 1 block/CU -> 16% occupancy).
//  - prefetch depth 2: B buffers b0/b1/b2 rotate (+12 VGPR, ~100 arch total,
//    below the ~130 allocator cliff) so ~350 cyc of work covers L2 latency.
// Block: 64 edges; waves = NOT n-groups x 2 K-halves.
template <int ILIM, int OC, int NOT, int BLK>
__global__ __launch_bounds__(BLK, 3)
void msg_mfma(const unsigned short* __restrict__ he,
              const float* __restrict__ nin,
              const int* __restrict__ src, const int* __restrict__ dst,
              const unsigned short* __restrict__ wp,
              float* __restrict__ agg) {
  constexpr int ZBYTES = ILIM * 64 * 2;
  constexpr int MBYTES = NOT * 32 * 32 * 4;
  constexpr int SBYTES = (ZBYTES > MBYTES ? ZBYTES : MBYTES);
  __shared__ char smem[SBYTES];                 // zb (K-loop) / mrg (epilogue)
  __shared__ int dst_s[64];
  unsigned short* zb = (unsigned short*)smem;   // [i][mt][h][qq*4+rr] bf16
  const int tid = threadIdx.x;
  const int e0 = blockIdx.x * 64;
  const int wid = tid >> 6, l = tid & 63, ln32 = l & 31, h = l >> 5;
  const int kh = wid & 1, wn = wid >> 1;
  const int kh3 = kh * 3;

  if (tid < 64) dst_s[tid] = dst[e0 + tid];

  // stage z (bf16), permuted: perm(e) = (e>>5)*32 + ((e>>2)&1)*16 + ((e>>3)&3)*4 + (e&3)
  {
    const int e = tid & 63, jj = tid >> 6;           // jj in [0, NOT*2)
    const int pe = ((e >> 5) << 5) + (((e >> 2) & 1) << 4) + (((e >> 3) & 3) << 2) + (e & 3);
    const float* zr = nin + (size_t)src[e0 + e] * ILIM;
    for (int p = jj; p < ILIM / 2; p += NOT * 2) {
      const float2 v = *(const float2*)(zr + 2 * p);
      zb[(2 * p) * 64 + pe] = rhu1(v.x);
      zb[(2 * p + 1) * 64 + pe] = rhu1(v.y);
    }
  }

  // A-fragments: he rows, this wave's K-half (32x32x16 A: m=lane&31, k=c*16+h*8+j)
  s16x8 af[2][3];
#pragma unroll
  for (int mt = 0; mt < 2; mt++) {
    const unsigned short* hr = he + (size_t)(e0 + mt * 32 + ln32) * 96 + kh * 48 + h * 8;
#pragma unroll
    for (int c = 0; c < 3; c++) af[mt][c] = *(const s16x8*)(hr + c * 16);
  }

  const unsigned short* wl = wp + l * 8;
  s16x8 b0[3], b1[3], b2[3];
  LOADB(0, b0);
  if (ILIM > 1) LOADB(1, b1);

  __syncthreads();   // zb/dst_s ready; no barriers in the K-loop

  f32x16 acc[2];
  acc[0] = (f32x16)0.f;
  acc[1] = (f32x16)0.f;

#pragma clang loop unroll(disable)
  for (int i = 0; i < ILIM; i += 3) {
    if (i + 2 < ILIM) LOADB(i + 2, b2);
    BODY(i, b0);
    if (i + 1 < ILIM) {
      if (i + 3 < ILIM) LOADB(i + 3, b0);
      BODY(i + 1, b1);
      if (i + 2 < ILIM) {
        if (i + 4 < ILIM) LOADB(i + 4, b1);
        BODY(i + 2, b2);
      }
    }
  }

  // epilogue: merge K-halves one m-tile at a time through smem (aliases zb),
  // then one atomicAdd per (e,o) — same atomic count as all prior rounds.
  __syncthreads();   // all zb reads complete; smem reused as mrg
  float* mrg = (float*)smem;   // [wn*32+row][32]
#pragma unroll
  for (int mt = 0; mt < 2; mt++) {
    if (kh) {
#pragma unroll
      for (int r = 0; r < 16; r++) {
        int row = (r & 3) + 8 * (r >> 2) + 4 * h;
        mrg[(wn * 32 + row) * 32 + ln32] = acc[mt][r];
      }
    }
    __syncthreads();
    if (!kh) {
      const int o = wn * 32 + ln32;
      if (o < OC) {
#pragma unroll
        for (int r = 0; r < 16; r++) {
          int row = (r & 3) + 8 * (r >> 2) + 4 * h;
          atomicAdd(agg + (size_t)dst_s[mt * 32 + row] * OC + o,
                    acc[mt][r] + mrg[(wn * 32 + row) * 32 + ln32]);
        }
      }
    }
    __syncthreads();
  }
}

// out[n][o] = relu(agg[n][o] + sum_i nin[n][i]*root[i][o] + bias[o])   (fp32 exact)
template <int IN_C, int OC>
__global__ void node_kernel(const float* __restrict__ agg, const float* __restrict__ nin,
                            const float* __restrict__ root, const float* __restrict__ bias,
                            float* __restrict__ out) {
  int idx = blockIdx.x * 256 + threadIdx.x;
  if (idx >= NN * OC) return;
  int n = idx / OC, o = idx - n * OC;
  float acc = agg[idx] + bias[o];
  const float* inp = nin + (size_t)n * IN_C;
#pragma unroll 6
  for (int i = 0; i < IN_C; i++) acc = fmaf(inp[i], root[i * OC + o], acc);
  out[idx] = fmaxf(acc, 0.f);
}

// per-graph: pool (batch sorted -> binary search) + fc1 + out
__global__ void pool_mlp_kernel(const float* __restrict__ h3, const int* __restrict__ batch,
                                const float* __restrict__ fc1_w, const float* __restrict__ fc1_b,
                                const float* __restrict__ out_w, const float* __restrict__ out_b,
                                float* __restrict__ out) {
  const int b = blockIdx.x;
  const int tid = threadIdx.x;
  __shared__ float g[45];
  __shared__ float go[90];
  __shared__ int rng[2];
  if (tid < 2) {
    int target = b + tid;
    int lo = 0, hi = NN;
    while (lo < hi) { int mid = (lo + hi) >> 1; if (batch[mid] < target) lo = mid + 1; else hi = mid; }
    rng[tid] = lo;
  }
  __syncthreads();
  const int s = rng[0], e = rng[1];
  if (tid < 45) {
    float acc = 0.f;
    for (int n = s; n < e; n++) acc += h3[n * 45 + tid];
    g[tid] = acc;
  }
  __syncthreads();
  if (tid < 90) {
    float acc = fc1_b[tid];
#pragma unroll 5
    for (int i = 0; i < 45; i++) acc = fmaf(g[i], fc1_w[i * 90 + tid], acc);
    go[tid] = fmaxf(acc, 0.f) * out_w[tid];
  }
  __syncthreads();
  if (tid == 0) {
    float acc = out_b[0];
    for (int i = 0; i < 90; i++) acc += go[i];
    out[b] = acc;
  }
}

extern "C" void kernel_launch(void* const* d_in, const int* in_sizes, int n_in,
                              void* d_out, int out_size, void* d_ws, size_t ws_size,
                              hipStream_t stream) {
  const float* x       = (const float*)d_in[0];
  const float* pos     = (const float*)d_in[1];
  const float* ea      = (const float*)d_in[2];
  const int*   eidx    = (const int*)d_in[3];
  const int*   batch   = (const int*)d_in[4];
  const float* c1_w1   = (const float*)d_in[5];
  const float* c1_b1   = (const float*)d_in[6];
  const float* c1_w2   = (const float*)d_in[7];
  const float* c1_b2   = (const float*)d_in[8];
  const float* c1_root = (const float*)d_in[9];
  const float* c1_bias = (const float*)d_in[10];
  const float* c2_w1   = (const float*)d_in[11];
  const float* c2_b1   = (const float*)d_in[12];
  const float* c2_w2   = (const float*)d_in[13];
  const float* c2_b2   = (const float*)d_in[14];
  const float* c2_root = (const float*)d_in[15];
  const float* c2_bias = (const float*)d_in[16];
  const float* c3_w1   = (const float*)d_in[17];
  const float* c3_b1   = (const float*)d_in[18];
  const float* c3_w2   = (const float*)d_in[19];
  const float* c3_b2   = (const float*)d_in[20];
  const float* c3_root = (const float*)d_in[21];
  const float* c3_bias = (const float*)d_in[22];
  const float* fc1_w   = (const float*)d_in[23];
  const float* fc1_b   = (const float*)d_in[24];
  const float* out_w   = (const float*)d_in[25];
  const float* out_b   = (const float*)d_in[26];
  const int* src = eidx;
  const int* dst = eidx + NE;

  // workspace carve
  float* ws  = (float*)d_ws;
  float* h0  = ws;                       // NN*16
  float* h1  = h0 + NN * 16;             // NN*90
  float* h2  = h1 + NN * 90;             // NN*90
  float* h3  = h2 + NN * 90;             // NN*45
  float* agg = h3 + NN * 45;             // NN*90
  unsigned short* he_bf = (unsigned short*)(agg + NN * 90);   // NE*96
  unsigned short* wp1 = he_bf + (size_t)NE * 96;              // 16*3*6*512
  unsigned short* wp2 = wp1 + (size_t)16 * 3 * 6 * 512;       // 90*3*6*512
  unsigned short* wp3 = wp2 + (size_t)90 * 3 * 6 * 512;       // 90*2*6*512

  concat_kernel<<<(NN * 16) / 256, 256, 0, stream>>>(x, pos, h0);

  wprep_frag32<90, 3><<<16, 256, 0, stream>>>(c1_w2, c1_b2, wp1, 16 * 90);
  wprep_frag32<90, 3><<<90, 256, 0, stream>>>(c2_w2, c2_b2, wp2, 90 * 90);
  wprep_frag32<45, 2><<<90, 256, 0, stream>>>(c3_w2, c3_b2, wp3, 90 * 45);

  // conv1: 16 -> 90   (64 edges/block; 6 waves = 3 n-groups x 2 K-halves)
  hipMemsetAsync(agg, 0, (size_t)NN * 90 * sizeof(float), stream);
  edge_mlp_bf<<<(NE * 96) / 256, 256, 0, stream>>>(ea, c1_w1, c1_b1, he_bf);
  msg_mfma<16, 90, 3, 384><<<NE / 64, 384, 0, stream>>>(he_bf, h0, src, dst, wp1, agg);
  node_kernel<16, 90><<<(NN * 90) / 256, 256, 0, stream>>>(agg, h0, c1_root, c1_bias, h1);

  // conv2: 90 -> 90
  hipMemsetAsync(agg, 0, (size_t)NN * 90 * sizeof(float), stream);
  edge_mlp_bf<<<(NE * 96) / 256, 256, 0, stream>>>(ea, c2_w1, c2_b1, he_bf);
  msg_mfma<90, 90, 3, 384><<<NE / 64, 384, 0, stream>>>(he_bf, h1, src, dst, wp2, agg);
  node_kernel<90, 90><<<(NN * 90) / 256, 256, 0, stream>>>(agg, h1, c2_root, c2_bias, h2);

  // conv3: 90 -> 45   (64 edges/block; 4 waves = 2 n-groups x 2 K-halves)
  hipMemsetAsync(agg, 0, (size_t)NN * 45 * sizeof(float), stream);
  edge_mlp_bf<<<(NE * 96) / 256, 256, 0, stream>>>(ea, c3_w1, c3_b1, he_bf);
  msg_mfma<90, 45, 2, 256><<<NE / 64, 256, 0, stream>>>(he_bf, h2, src, dst, wp3, agg);
  node_kernel<90, 45><<<(NN * 45 + 255) / 256, 256, 0, stream>>>(agg, h2, c3_root, c3_bias, h3);

  pool_mlp_kernel<<<NG, 128, 0, stream>>>(h3, batch, fc1_w, fc1_b, out_w, out_b, (float*)d_out);
}

// Round 13
// 602.972 us; speedup vs baseline: 1.9075x; 1.9075x over previous
//
#include <hip/hip_runtime.h>

#define NN 16000   // nodes
#define NE 64000   // edges
#define HD 90      // hidden
#define NG 512     // graphs

typedef float f32x4 __attribute__((ext_vector_type(4)));
typedef float f32x16 __attribute__((ext_vector_type(16)));
typedef short s16x8 __attribute__((ext_vector_type(8)));

// round-half-up f32 -> bf16
__device__ __forceinline__ unsigned short rhu1(float f) {
  return (unsigned short)((__builtin_bit_cast(unsigned int, f) + 0x8000u) >> 16);
}
// pack two f32 -> bf16x2 (lo in low half), RHU rounding
__device__ __forceinline__ unsigned int rhu_pack(float lo, float hi) {
  unsigned int ul = __builtin_bit_cast(unsigned int, lo) + 0x8000u;
  unsigned int uh = __builtin_bit_cast(unsigned int, hi) + 0x8000u;
  return __builtin_amdgcn_perm(uh, ul, 0x07060302u);
}
__device__ __forceinline__ float bfhi(unsigned int u) {
  return __builtin_bit_cast(float, u & 0xFFFF0000u);
}
__device__ __forceinline__ float bflo(unsigned int u) {
  return __builtin_bit_cast(float, u << 16);
}

// h0 = concat(x, pos) : [NN, 16]
__global__ void concat_kernel(const float* __restrict__ x, const float* __restrict__ pos,
                              float* __restrict__ h0) {
  int idx = blockIdx.x * 256 + threadIdx.x;
  if (idx >= NN * 16) return;
  int n = idx >> 4, c = idx & 15;
  h0[idx] = (c < 13) ? x[n * 13 + c] : pos[n * 3 + (c - 13)];
}

// he_bf[e][k] : [NE, 96] bf16. k<90: relu(edge MLP); k==90: 1.0 (bias row); k>90: 0
__global__ void edge_mlp_bf(const float* __restrict__ ea, const float* __restrict__ w1,
                            const float* __restrict__ b1, unsigned short* __restrict__ he) {
  int idx = blockIdx.x * 256 + threadIdx.x;
  if (idx >= NE * 96) return;
  int e = idx / 96, k = idx - e * 96;
  unsigned short v;
  if (k < 90) {
    const float* a = ea + e * 8;
    float acc = b1[k];
#pragma unroll
    for (int j = 0; j < 8; j++) acc = fmaf(a[j], w1[j * HD + k], acc);
    v = rhu1(fmaxf(acc, 0.f));
  } else {
    v = (k == 90) ? (unsigned short)0x3F80 : (unsigned short)0;  // bf16(1.0) / 0
  }
  he[idx] = v;
}

// W' prep, 32x32x16 B-fragment order: shorts as [i][ot(NOT)][c(6)][lane(64)][j(8)]
//   o = ot*32 + (lane&31), hk = c*16 + (lane>>5)*8 + j
//   hk<90 -> w2[hk][i*OC+o]; hk==90 -> b2[i*OC+o]; else 0.  One block per i.
template <int OC, int NOT>
__global__ void wprep_frag32(const float* __restrict__ w2, const float* __restrict__ b2,
                             unsigned short* __restrict__ wout, int inc_oc) {
  const int i = blockIdx.x;
  unsigned int* wo = (unsigned int*)(wout + (size_t)i * NOT * 6 * 512);
  for (int u = threadIdx.x; u < NOT * 6 * 256; u += 256) {
    int f = u >> 8, r = u & 255;
    int ot = f / 6;
    int c = f - 6 * ot;
    int lane = r >> 2, uu = r & 3;
    int o = ot * 32 + (lane & 31);
    int hk = c * 16 + ((lane >> 5) << 3) + 2 * uu;
    float v0 = 0.f, v1 = 0.f;
    if (o < OC) {
      if (hk < 90) v0 = w2[hk * inc_oc + i * OC + o];
      else if (hk == 90) v0 = b2[i * OC + o];
      int hk1 = hk + 1;
      if (hk1 < 90) v1 = w2[hk1 * inc_oc + i * OC + o];
      else if (hk1 == 90) v1 = b2[i * OC + o];
    }
    wo[u] = rhu_pack(v0, v1);
  }
}

// ---- msg kernel pipeline macros (plain arrays, constant post-unroll indices) ----
#define LOADB(II, B)                                                           \
  do {                                                                         \
    const unsigned short* wg_ = wl + ((size_t)((II) * NOT + wn) * 6 + kh3) * 512; \
    B[0] = *(const s16x8*)(wg_);                                               \
    B[1] = *(const s16x8*)(wg_ + 512);                                         \
    B[2] = *(const s16x8*)(wg_ + 1024);                                        \
  } while (0)

#define BODY(II, B)                                                            \
  do {                                                                         \
    _Pragma("unroll")                                                          \
    for (int mt = 0; mt < 2; mt++) {                                           \
      const int zbase = (II) * 64 + mt * 32 + h * 16;                          \
      const uint4 za = *(const uint4*)&zb[zbase];                              \
      const uint4 zc = *(const uint4*)&zb[zbase + 8];                          \
      f32x16 t = __builtin_amdgcn_mfma_f32_32x32x16_bf16(af[mt][0], B[0], (f32x16)0.f, 0, 0, 0); \
      t = __builtin_amdgcn_mfma_f32_32x32x16_bf16(af[mt][1], B[1], t, 0, 0, 0);\
      t = __builtin_amdgcn_mfma_f32_32x32x16_bf16(af[mt][2], B[2], t, 0, 0, 0);\
      f32x16 zv;                                                               \
      zv[0] = bflo(za.x);  zv[1] = bfhi(za.x);  zv[2] = bflo(za.y);  zv[3] = bfhi(za.y); \
      zv[4] = bflo(za.z);  zv[5] = bfhi(za.z);  zv[6] = bflo(za.w);  zv[7] = bfhi(za.w); \
      zv[8] = bflo(zc.x);  zv[9] = bfhi(zc.x);  zv[10] = bflo(zc.y); zv[11] = bfhi(zc.y); \
      zv[12] = bflo(zc.z); zv[13] = bfhi(zc.z); zv[14] = bflo(zc.w); zv[15] = bfhi(zc.w); \
      acc[mt] += zv * t;                                                       \
    }                                                                          \
  } while (0)

// Fused message GEMM + scatter, i-outer, barrier-free K-loop, 32x32x16 core,
// K-split wave specialization. Composition of the two PROVEN pieces:
//  - K-loop: R11's depth-2 pipeline verbatim (b0/b1, i+=2) — compiled to
//    76 VGPR, zero spill. (R12's depth-3 hit the ~85-VGPR allocator target ->
//    186 MB scratch. Envelope: <= ~76 arch VGPRs for 384-thread blocks.)
//  - Epilogue/LDS: R12's aliased merge (12.8 KB total) — R11's 36 KB LDS
//    capped residency at 1 block/CU (16% occ), the latency-hiding killer.
// Block: 64 edges; waves = NOT n-groups x 2 K-halves.
template <int ILIM, int OC, int NOT, int BLK>
__global__ __launch_bounds__(BLK, 3)
void msg_mfma(const unsigned short* __restrict__ he,
              const float* __restrict__ nin,
              const int* __restrict__ src, const int* __restrict__ dst,
              const unsigned short* __restrict__ wp,
              float* __restrict__ agg) {
  constexpr int ZBYTES = ILIM * 64 * 2;
  constexpr int MBYTES = NOT * 32 * 32 * 4;
  constexpr int SBYTES = (ZBYTES > MBYTES ? ZBYTES : MBYTES);
  __shared__ char smem[SBYTES];                 // zb (K-loop) / mrg (epilogue)
  __shared__ int dst_s[64];
  unsigned short* zb = (unsigned short*)smem;   // [i][mt][h][qq*4+rr] bf16
  const int tid = threadIdx.x;
  const int e0 = blockIdx.x * 64;
  const int wid = tid >> 6, l = tid & 63, ln32 = l & 31, h = l >> 5;
  const int kh = wid & 1, wn = wid >> 1;
  const int kh3 = kh * 3;

  if (tid < 64) dst_s[tid] = dst[e0 + tid];

  // stage z (bf16), permuted: perm(e) = (e>>5)*32 + ((e>>2)&1)*16 + ((e>>3)&3)*4 + (e&3)
  {
    const int e = tid & 63, jj = tid >> 6;           // jj in [0, NOT*2)
    const int pe = ((e >> 5) << 5) + (((e >> 2) & 1) << 4) + (((e >> 3) & 3) << 2) + (e & 3);
    const float* zr = nin + (size_t)src[e0 + e] * ILIM;
    for (int p = jj; p < ILIM / 2; p += NOT * 2) {
      const float2 v = *(const float2*)(zr + 2 * p);
      zb[(2 * p) * 64 + pe] = rhu1(v.x);
      zb[(2 * p + 1) * 64 + pe] = rhu1(v.y);
    }
  }

  // A-fragments: he rows, this wave's K-half (32x32x16 A: m=lane&31, k=c*16+h*8+j)
  s16x8 af[2][3];
#pragma unroll
  for (int mt = 0; mt < 2; mt++) {
    const unsigned short* hr = he + (size_t)(e0 + mt * 32 + ln32) * 96 + kh * 48 + h * 8;
#pragma unroll
    for (int c = 0; c < 3; c++) af[mt][c] = *(const s16x8*)(hr + c * 16);
  }

  const unsigned short* wl = wp + l * 8;
  s16x8 b0[3], b1[3];
  LOADB(0, b0);

  __syncthreads();   // zb/dst_s ready; no barriers in the K-loop

  f32x16 acc[2];
  acc[0] = (f32x16)0.f;
  acc[1] = (f32x16)0.f;

#pragma clang loop unroll(disable)
  for (int i = 0; i < ILIM; i += 2) {
    if (i + 1 < ILIM) LOADB(i + 1, b1);   // full-iteration prefetch depth
    BODY(i, b0);
    if (i + 1 < ILIM) {
      if (i + 2 < ILIM) LOADB(i + 2, b0);
      BODY(i + 1, b1);
    }
  }

  // epilogue: merge K-halves one m-tile at a time through smem (aliases zb),
  // then one atomicAdd per (e,o) — same atomic count as all prior rounds.
  __syncthreads();   // all zb reads complete; smem reused as mrg
  float* mrg = (float*)smem;   // [wn*32+row][32]
#pragma unroll
  for (int mt = 0; mt < 2; mt++) {
    if (kh) {
#pragma unroll
      for (int r = 0; r < 16; r++) {
        int row = (r & 3) + 8 * (r >> 2) + 4 * h;
        mrg[(wn * 32 + row) * 32 + ln32] = acc[mt][r];
      }
    }
    __syncthreads();
    if (!kh) {
      const int o = wn * 32 + ln32;
      if (o < OC) {
#pragma unroll
        for (int r = 0; r < 16; r++) {
          int row = (r & 3) + 8 * (r >> 2) + 4 * h;
          atomicAdd(agg + (size_t)dst_s[mt * 32 + row] * OC + o,
                    acc[mt][r] + mrg[(wn * 32 + row) * 32 + ln32]);
        }
      }
    }
    __syncthreads();
  }
}

// out[n][o] = relu(agg[n][o] + sum_i nin[n][i]*root[i][o] + bias[o])   (fp32 exact)
template <int IN_C, int OC>
__global__ void node_kernel(const float* __restrict__ agg, const float* __restrict__ nin,
                            const float* __restrict__ root, const float* __restrict__ bias,
                            float* __restrict__ out) {
  int idx = blockIdx.x * 256 + threadIdx.x;
  if (idx >= NN * OC) return;
  int n = idx / OC, o = idx - n * OC;
  float acc = agg[idx] + bias[o];
  const float* inp = nin + (size_t)n * IN_C;
#pragma unroll 6
  for (int i = 0; i < IN_C; i++) acc = fmaf(inp[i], root[i * OC + o], acc);
  out[idx] = fmaxf(acc, 0.f);
}

// per-graph: pool (batch sorted -> binary search) + fc1 + out
__global__ void pool_mlp_kernel(const float* __restrict__ h3, const int* __restrict__ batch,
                                const float* __restrict__ fc1_w, const float* __restrict__ fc1_b,
                                const float* __restrict__ out_w, const float* __restrict__ out_b,
                                float* __restrict__ out) {
  const int b = blockIdx.x;
  const int tid = threadIdx.x;
  __shared__ float g[45];
  __shared__ float go[90];
  __shared__ int rng[2];
  if (tid < 2) {
    int target = b + tid;
    int lo = 0, hi = NN;
    while (lo < hi) { int mid = (lo + hi) >> 1; if (batch[mid] < target) lo = mid + 1; else hi = mid; }
    rng[tid] = lo;
  }
  __syncthreads();
  const int s = rng[0], e = rng[1];
  if (tid < 45) {
    float acc = 0.f;
    for (int n = s; n < e; n++) acc += h3[n * 45 + tid];
    g[tid] = acc;
  }
  __syncthreads();
  if (tid < 90) {
    float acc = fc1_b[tid];
#pragma unroll 5
    for (int i = 0; i < 45; i++) acc = fmaf(g[i], fc1_w[i * 90 + tid], acc);
    go[tid] = fmaxf(acc, 0.f) * out_w[tid];
  }
  __syncthreads();
  if (tid == 0) {
    float acc = out_b[0];
    for (int i = 0; i < 90; i++) acc += go[i];
    out[b] = acc;
  }
}

extern "C" void kernel_launch(void* const* d_in, const int* in_sizes, int n_in,
                              void* d_out, int out_size, void* d_ws, size_t ws_size,
                              hipStream_t stream) {
  const float* x       = (const float*)d_in[0];
  const float* pos     = (const float*)d_in[1];
  const float* ea      = (const float*)d_in[2];
  const int*   eidx    = (const int*)d_in[3];
  const int*   batch   = (const int*)d_in[4];
  const float* c1_w1   = (const float*)d_in[5];
  const float* c1_b1   = (const float*)d_in[6];
  const float* c1_w2   = (const float*)d_in[7];
  const float* c1_b2   = (const float*)d_in[8];
  const float* c1_root = (const float*)d_in[9];
  const float* c1_bias = (const float*)d_in[10];
  const float* c2_w1   = (const float*)d_in[11];
  const float* c2_b1   = (const float*)d_in[12];
  const float* c2_w2   = (const float*)d_in[13];
  const float* c2_b2   = (const float*)d_in[14];
  const float* c2_root = (const float*)d_in[15];
  const float* c2_bias = (const float*)d_in[16];
  const float* c3_w1   = (const float*)d_in[17];
  const float* c3_b1   = (const float*)d_in[18];
  const float* c3_w2   = (const float*)d_in[19];
  const float* c3_b2   = (const float*)d_in[20];
  const float* c3_root = (const float*)d_in[21];
  const float* c3_bias = (const float*)d_in[22];
  const float* fc1_w   = (const float*)d_in[23];
  const float* fc1_b   = (const float*)d_in[24];
  const float* out_w   = (const float*)d_in[25];
  const float* out_b   = (const float*)d_in[26];
  const int* src = eidx;
  const int* dst = eidx + NE;

  // workspace carve
  float* ws  = (float*)d_ws;
  float* h0  = ws;                       // NN*16
  float* h1  = h0 + NN * 16;             // NN*90
  float* h2  = h1 + NN * 90;             // NN*90
  float* h3  = h2 + NN * 90;             // NN*45
  float* agg = h3 + NN * 45;             // NN*90
  unsigned short* he_bf = (unsigned short*)(agg + NN * 90);   // NE*96
  unsigned short* wp1 = he_bf + (size_t)NE * 96;              // 16*3*6*512
  unsigned short* wp2 = wp1 + (size_t)16 * 3 * 6 * 512;       // 90*3*6*512
  unsigned short* wp3 = wp2 + (size_t)90 * 3 * 6 * 512;       // 90*2*6*512

  concat_kernel<<<(NN * 16) / 256, 256, 0, stream>>>(x, pos, h0);

  wprep_frag32<90, 3><<<16, 256, 0, stream>>>(c1_w2, c1_b2, wp1, 16 * 90);
  wprep_frag32<90, 3><<<90, 256, 0, stream>>>(c2_w2, c2_b2, wp2, 90 * 90);
  wprep_frag32<45, 2><<<90, 256, 0, stream>>>(c3_w2, c3_b2, wp3, 90 * 45);

  // conv1: 16 -> 90   (64 edges/block; 6 waves = 3 n-groups x 2 K-halves)
  hipMemsetAsync(agg, 0, (size_t)NN * 90 * sizeof(float), stream);
  edge_mlp_bf<<<(NE * 96) / 256, 256, 0, stream>>>(ea, c1_w1, c1_b1, he_bf);
  msg_mfma<16, 90, 3, 384><<<NE / 64, 384, 0, stream>>>(he_bf, h0, src, dst, wp1, agg);
  node_kernel<16, 90><<<(NN * 90) / 256, 256, 0, stream>>>(agg, h0, c1_root, c1_bias, h1);

  // conv2: 90 -> 90
  hipMemsetAsync(agg, 0, (size_t)NN * 90 * sizeof(float), stream);
  edge_mlp_bf<<<(NE * 96) / 256, 256, 0, stream>>>(ea, c2_w1, c2_b1, he_bf);
  msg_mfma<90, 90, 3, 384><<<NE / 64, 384, 0, stream>>>(he_bf, h1, src, dst, wp2, agg);
  node_kernel<90, 90><<<(NN * 90) / 256, 256, 0, stream>>>(agg, h1, c2_root, c2_bias, h2);

  // conv3: 90 -> 45   (64 edges/block; 4 waves = 2 n-groups x 2 K-halves)
  hipMemsetAsync(agg, 0, (size_t)NN * 45 * sizeof(float), stream);
  edge_mlp_bf<<<(NE * 96) / 256, 256, 0, stream>>>(ea, c3_w1, c3_b1, he_bf);
  msg_mfma<90, 45, 2, 256><<<NE / 64, 256, 0, stream>>>(he_bf, h2, src, dst, wp3, agg);
  node_kernel<90, 45><<<(NN * 45 + 255) / 256, 256, 0, stream>>>(agg, h2, c3_root, c3_bias, h3);

  pool_mlp_kernel<<<NG, 128, 0, stream>>>(h3, batch, fc1_w, fc1_b, out_w, out_b, (float*)d_out);
}